// Round 3
// baseline (235.057 us; speedup 1.0000x reference)
//
#include <hip/hip_runtime.h>
#include <math.h>

#define NBINS 10
#define PP    8
#define NB    32
#define HH    512
#define WW    512
#define HC    64          // HH/PP
#define WC    64
#define NBR   63          // HC - 2 + 1
#define NBC   63
#define EPS2  1e-10       // EPS*EPS, EPS=1e-5

// ---------------------------------------------------------------------------
// K0: zero the atomic accumulators (d_ws is re-poisoned to 0xAA every call)
// ---------------------------------------------------------------------------
__global__ void k_init(double* __restrict__ Q, double* __restrict__ s2) {
    int idx = blockIdx.x * blockDim.x + threadIdx.x;
    if (idx < HC * WC)   Q[idx]  = 0.0;
    if (idx < NBR * NBC) s2[idx] = 0.0;
}

// ---------------------------------------------------------------------------
// K1: fused Sobel-conv + atan2 binning + 8x8 mean pool -> cell[n][bin][cy][cx]
// Bin DECISIONS emulate the reference's float32 pipeline bit-exactly:
//   - f32 conv, ascending row-major accumulation chain (mul exact for +-1,+-2)
//   - correctly-rounded atan2f via (float)atan2(double,double)
//   - pbin = (phase / (float)pi) * 10.0f in f32 IEEE ops, floorf/ceilf
// Smooth quantities (mag, pooling) stay in f64 (noise ~1e-6, irrelevant).
// ---------------------------------------------------------------------------
__global__ __launch_bounds__(64) void k_cellhist(const float* __restrict__ img,
                                                 double* __restrict__ cell) {
    const int cy = blockIdx.x;   // 0..63
    const int n  = blockIdx.y;   // 0..31
    const int t  = threadIdx.x;  // 0..63

    __shared__ float lds[10][520];   // stride 520: 520%32==8 (col decides bank)

    const float* im = img + (size_t)n * HH * WW;
    const int gy0 = cy * PP - 1;
    for (int idx = t; idx < 10 * 514; idx += 64) {
        int r  = idx / 514;
        int c  = idx % 514 - 1;      // -1 .. 512
        int gr = gy0 + r;
        float v = 0.0f;
        if ((unsigned)gr < HH && (unsigned)c < WW) v = im[gr * WW + c];
        lds[r][c + 1] = v;
    }
    __syncthreads();

    double hist[NBINS];
#pragma unroll
    for (int b = 0; b < NBINS; ++b) hist[b] = 0.0;

    const float pi32 = (float)M_PI;   // 3.14159274f
    const int cx = t;
    for (int py = 0; py < PP; ++py) {
        const int row = py + 1;
        for (int k = 0; k < PP; ++k) {
            // stagger px by (t>>2) so 64 lanes spread over all 32 banks
            const int px  = (k + (t >> 2)) & 7;
            const int col = cx * PP + px + 1;
            float a  = lds[row - 1][col - 1];
            float b  = lds[row - 1][col    ];
            float c  = lds[row - 1][col + 1];
            float d  = lds[row    ][col - 1];
            float f  = lds[row    ][col + 1];
            float g  = lds[row + 1][col - 1];
            float h  = lds[row + 1][col    ];
            float i2 = lds[row + 1][col + 1];
            // chan0 weights m = [[1,0,-1],[2,0,-2],[1,0,-1]], ascending (dy,dx)
            float gA = a;
            gA = gA - c;
            gA = gA + 2.0f * d;
            gA = gA - 2.0f * f;
            gA = gA + g;
            gA = gA - i2;
            // chan1 weights m.T = [[1,2,1],[0,0,0],[-1,-2,-1]]
            float gB = a;
            gB = gB + 2.0f * b;
            gB = gB + c;
            gB = gB - g;
            gB = gB - 2.0f * h;
            gB = gB - i2;
            // correctly-rounded f32 atan2 via f64
            float phase = (float)atan2((double)gA, (double)gB);
            float pb = phase / pi32;   // f32 IEEE division (no fast-math)
            pb = pb * 10.0f;           // f32 multiply
            int fl = (int)floorf(pb);
            int ce = (int)ceilf(pb);
            int flm = fl % NBINS; if (flm < 0) flm += NBINS;   // Python %
            int cem = ce % NBINS; if (cem < 0) cem += NBINS;
            double mag = sqrt((double)gA * (double)gA + (double)gB * (double)gB);
            hist[flm] += mag;
            hist[cem] += 1.0 - mag;
        }
    }

#pragma unroll
    for (int b = 0; b < NBINS; ++b)
        cell[(((size_t)n * NBINS + b) * HC + cy) * WC + cx] = hist[b] * (1.0 / 64.0);
}

// ---------------------------------------------------------------------------
// K2: Q[i][j] = sum over (n,bin) of cell^2   (64x64), atomic over nb-chunks
// ---------------------------------------------------------------------------
__global__ __launch_bounds__(64) void k_Q(const double* __restrict__ cell,
                                          double* __restrict__ Q) {
    const int i     = blockIdx.x;   // 0..63
    const int chunk = blockIdx.y;   // 0..9
    const int j     = threadIdx.x;  // 0..63
    double acc = 0.0;
    for (int nb = chunk * 32; nb < chunk * 32 + 32; ++nb) {
        double v = cell[((size_t)nb * HC + i) * WC + j];
        acc += v * v;
    }
    atomicAdd(&Q[i * WC + j], acc);
}

// ---------------------------------------------------------------------------
// K3: s[i][j] = 2x2 window sum of Q; inv1 = 1/sqrt(s + EPS^2)   (63x63)
// ---------------------------------------------------------------------------
__global__ void k_s_inv1(const double* __restrict__ Q, double* __restrict__ inv1) {
    int idx = blockIdx.x * blockDim.x + threadIdx.x;
    if (idx >= NBR * NBC) return;
    int r = idx / NBC, c = idx % NBC;
    double s = Q[r * WC + c] + Q[r * WC + c + 1] +
               Q[(r + 1) * WC + c] + Q[(r + 1) * WC + c + 1];
    inv1[idx] = 1.0 / sqrt(s + EPS2);
}

// ---------------------------------------------------------------------------
// K4: s2[i][j] = sum over (n,bin,di,dj) of min(cell*inv1, 0.2)^2
// ---------------------------------------------------------------------------
__global__ __launch_bounds__(64) void k_s2(const double* __restrict__ cell,
                                           const double* __restrict__ inv1,
                                           double* __restrict__ s2) {
    const int i     = blockIdx.x;   // 0..62
    const int chunk = blockIdx.y;   // 0..19
    const int j     = threadIdx.x;  // 0..63
    if (j >= NBC) return;
    const double w = inv1[i * NBC + j];
    double acc = 0.0;
    for (int nb = chunk * 16; nb < chunk * 16 + 16; ++nb) {
#pragma unroll
        for (int di = 0; di < 2; ++di)
#pragma unroll
            for (int dj = 0; dj < 2; ++dj) {
                double v = cell[((size_t)nb * HC + i + di) * WC + j + dj] * w;
                v = fmin(v, 0.2);
                acc += v * v;
            }
    }
    atomicAdd(&s2[i * NBC + j], acc);
}

// ---------------------------------------------------------------------------
// K5: inv2 = 1/sqrt(s2 + EPS^2)
// ---------------------------------------------------------------------------
__global__ void k_inv2(const double* __restrict__ s2, double* __restrict__ inv2) {
    int idx = blockIdx.x * blockDim.x + threadIdx.x;
    if (idx >= NBR * NBC) return;
    inv2[idx] = 1.0 / sqrt(s2[idx] + EPS2);
}

// ---------------------------------------------------------------------------
// K6: final feature write: out[n][bin][di][dj][i][j]  (5,080,320 f32)
// ---------------------------------------------------------------------------
__global__ void k_out(const double* __restrict__ cell,
                      const double* __restrict__ inv1,
                      const double* __restrict__ inv2,
                      float* __restrict__ out) {
    int idx = blockIdx.x * blockDim.x + threadIdx.x;
    const int total = NB * NBINS * 2 * 2 * NBR * NBC;
    if (idx >= total) return;
    int j   = idx % NBC;
    int tmp = idx / NBC;
    int i   = tmp % NBR; tmp /= NBR;
    int dj  = tmp % 2;   tmp /= 2;
    int di  = tmp % 2;   tmp /= 2;
    int b   = tmp % NBINS;
    int n   = tmp / NBINS;
    double v = cell[(((size_t)n * NBINS + b) * HC + i + di) * WC + j + dj]
               * inv1[i * NBC + j];
    v = fmin(v, 0.2);
    out[idx] = (float)(v * inv2[i * NBC + j]);
}

// ---------------------------------------------------------------------------
extern "C" void kernel_launch(void* const* d_in, const int* in_sizes, int n_in,
                              void* d_out, int out_size, void* d_ws, size_t ws_size,
                              hipStream_t stream) {
    const float* img = (const float*)d_in[0];   // (32,1,512,512) f32
    // d_in[1] is the fixed Sobel pair; coefficients are hardcoded above.
    float* out = (float*)d_out;

    double* cell = (double*)d_ws;                        // 32*10*64*64
    double* Q    = cell + (size_t)NB * NBINS * HC * WC;  // 64*64
    double* s2   = Q + HC * WC;                          // 63*63
    double* inv1 = s2 + NBR * NBC;                       // 63*63
    double* inv2 = inv1 + NBR * NBC;                     // 63*63

    hipLaunchKernelGGL(k_init, dim3(16), dim3(256), 0, stream, Q, s2);
    hipLaunchKernelGGL(k_cellhist, dim3(HC, NB), dim3(64), 0, stream, img, cell);
    hipLaunchKernelGGL(k_Q, dim3(HC, 10), dim3(64), 0, stream, cell, Q);
    hipLaunchKernelGGL(k_s_inv1, dim3(16), dim3(256), 0, stream, Q, inv1);
    hipLaunchKernelGGL(k_s2, dim3(NBR, 20), dim3(64), 0, stream, cell, inv1, s2);
    hipLaunchKernelGGL(k_inv2, dim3(16), dim3(256), 0, stream, s2, inv2);
    const int total = NB * NBINS * 2 * 2 * NBR * NBC;
    hipLaunchKernelGGL(k_out, dim3((total + 255) / 256), dim3(256), 0, stream,
                       cell, inv1, inv2, out);
}

// Round 4
// 168.171 us; speedup vs baseline: 1.3977x; 1.3977x over previous
//
#include <hip/hip_runtime.h>
#include <math.h>

#define NBINS 10
#define NB    32
#define HH    512
#define WW    512
#define HC    64
#define WC    64
#define NBR   63
#define NBC   63
#define EPS2  1e-10       // EPS^2, EPS=1e-5

// ---------------------------------------------------------------------------
// K0: zero the f64 atomic accumulators (d_ws is re-poisoned each call)
// ---------------------------------------------------------------------------
__global__ void k_init(double* __restrict__ Q, double* __restrict__ s2) {
    int idx = blockIdx.x * blockDim.x + threadIdx.x;
    if (idx < HC * WC)   Q[idx]  = 0.0;
    if (idx < NBR * NBC) s2[idx] = 0.0;
}

// ---------------------------------------------------------------------------
// K1: fused Sobel + binning + 8x8 mean pool -> cell[n][bin][cy][cx] (f32)
// Block = (cy, half, n): 32 cells, 64 threads = 2 per cell (4 rows each),
// merged via shfl_xor(1). Bin decisions: fast f32 atan2f with a 1e-4 guard
// band around integer pbin; guard failures fall back to the round-3-exact
// f32-emulation path ((float)atan2(double,double) etc.) which passed.
// Conv chains are source-identical to the passing round-3 kernel.
// ---------------------------------------------------------------------------
__global__ __launch_bounds__(64) void k_cellhist(const float* __restrict__ img,
                                                 float* __restrict__ cell) {
    const int cy   = blockIdx.x;   // 0..63
    const int half = blockIdx.y;   // 0..1
    const int n    = blockIdx.z;   // 0..31
    const int t    = threadIdx.x;  // 0..63

    __shared__ float lds[10][264];   // 264 % 32 == 8; <=2-way conflicts w/ stagger

    const float* im = img + (size_t)n * HH * WW;
    const int gy0 = cy * 8 - 1;
    const int gx0 = half * 256 - 1;
    for (int idx = t; idx < 10 * 258; idx += 64) {
        int r  = idx / 258;
        int c  = idx - r * 258;
        int gr = gy0 + r, gc = gx0 + c;
        float v = 0.0f;
        if ((unsigned)gr < HH && (unsigned)gc < WW) v = im[gr * WW + gc];
        lds[r][c] = v;
    }
    __syncthreads();

    float hist[NBINS];
#pragma unroll
    for (int b = 0; b < NBINS; ++b) hist[b] = 0.0f;

    const float pi32 = (float)M_PI;      // 0x40490FDB
    const int cc   = t >> 1;             // local cell col 0..31
    const int r0   = (t & 1) * 4 + 1;    // rows 1-4 or 5-8 of the strip
    const int stag = t >> 2;

    for (int ry = 0; ry < 4; ++ry) {
        const int row = r0 + ry;
        for (int k = 0; k < 8; ++k) {
            const int px  = (k + stag) & 7;
            const int col = cc * 8 + px + 1;
            float a  = lds[row - 1][col - 1];
            float b  = lds[row - 1][col    ];
            float c  = lds[row - 1][col + 1];
            float d  = lds[row    ][col - 1];
            float f  = lds[row    ][col + 1];
            float g  = lds[row + 1][col - 1];
            float h  = lds[row + 1][col    ];
            float i2 = lds[row + 1][col + 1];
            // identical accumulation order to the passing round-3 kernel
            float gA = a;
            gA = gA - c;
            gA = gA + 2.0f * d;
            gA = gA - 2.0f * f;
            gA = gA + g;
            gA = gA - i2;
            float gB = a;
            gB = gB + 2.0f * b;
            gB = gB + c;
            gB = gB - g;
            gB = gB - 2.0f * h;
            gB = gB - i2;

            float mag = sqrtf(gA * gA + gB * gB);

            // fast bin decision with guard band
            float pbf = atan2f(gA, gB);
            pbf = pbf / pi32;
            pbf = pbf * 10.0f;
            float fr  = floorf(pbf);
            float dfr = pbf - fr;
            int fl, ce;
            if (dfr > 1e-4f && dfr < 0.9999f) {
                fl = (int)fr;
                ce = fl + 1;
            } else {
                // exact f32-emulation fallback (round-3 verified)
                float phase = (float)atan2((double)gA, (double)gB);
                float pb = phase / pi32;
                pb = pb * 10.0f;
                fl = (int)floorf(pb);
                ce = (int)ceilf(pb);
            }
            int flm = fl % NBINS; if (flm < 0) flm += NBINS;   // Python %
            int cem = ce % NBINS; if (cem < 0) cem += NBINS;
            hist[flm] += mag;
            hist[cem] += 1.0f - mag;
        }
    }

    // merge the two half-cell histograms (lanes 2c, 2c+1)
#pragma unroll
    for (int b = 0; b < NBINS; ++b) hist[b] += __shfl_xor(hist[b], 1);

    const int cx = half * 32 + cc;
    const int bb0 = (t & 1) * 5;     // even lanes write bins 0-4, odd 5-9
#pragma unroll
    for (int b = 0; b < 5; ++b) {
        int bb = bb0 + b;
        cell[(((size_t)n * NBINS + bb) * HC + cy) * WC + cx] = hist[bb] * 0.015625f;
    }
}

// ---------------------------------------------------------------------------
// K2: Q[i][j] = sum over (n,bin) of cell^2, f64 atomic over nb-chunks
// ---------------------------------------------------------------------------
__global__ __launch_bounds__(64) void k_Q(const float* __restrict__ cell,
                                          double* __restrict__ Q) {
    const int i     = blockIdx.x;   // 0..63
    const int chunk = blockIdx.y;   // 0..9
    const int j     = threadIdx.x;  // 0..63
    double acc = 0.0;
    for (int nb = chunk * 32; nb < chunk * 32 + 32; ++nb) {
        double v = (double)cell[((size_t)nb * HC + i) * WC + j];
        acc += v * v;
    }
    atomicAdd(&Q[i * WC + j], acc);
}

// ---------------------------------------------------------------------------
// K4: s2[i][j] = sum over (n,bin,di,dj) of min(cell*inv1, 0.2)^2
//     inv1 recomputed inline from Q (bit-identical expression to k_out's)
// ---------------------------------------------------------------------------
__global__ __launch_bounds__(64) void k_s2(const float* __restrict__ cell,
                                           const double* __restrict__ Q,
                                           double* __restrict__ s2) {
    const int i     = blockIdx.x;   // 0..62
    const int chunk = blockIdx.y;   // 0..19
    const int j     = threadIdx.x;  // 0..63
    if (j >= NBC) return;
    double s = Q[i * WC + j] + Q[i * WC + j + 1] +
               Q[(i + 1) * WC + j] + Q[(i + 1) * WC + j + 1];
    double w = 1.0 / sqrt(s + EPS2);
    double acc = 0.0;
    for (int nb = chunk * 16; nb < chunk * 16 + 16; ++nb) {
#pragma unroll
        for (int di = 0; di < 2; ++di)
#pragma unroll
            for (int dj = 0; dj < 2; ++dj) {
                double v = (double)cell[((size_t)nb * HC + i + di) * WC + j + dj] * w;
                v = fmin(v, 0.2);
                acc += v * v;
            }
    }
    atomicAdd(&s2[i * NBC + j], acc);
}

// ---------------------------------------------------------------------------
// K6: final write out[n][bin][di][dj][i][j]; inv1/inv2 recomputed inline
// ---------------------------------------------------------------------------
__global__ void k_out(const float* __restrict__ cell,
                      const double* __restrict__ Q,
                      const double* __restrict__ s2,
                      float* __restrict__ out) {
    int idx = blockIdx.x * blockDim.x + threadIdx.x;
    const int total = NB * NBINS * 2 * 2 * NBR * NBC;
    if (idx >= total) return;
    int j   = idx % NBC;
    int tmp = idx / NBC;
    int i   = tmp % NBR; tmp /= NBR;
    int dj  = tmp % 2;   tmp /= 2;
    int di  = tmp % 2;   tmp /= 2;
    int b   = tmp % NBINS;
    int n   = tmp / NBINS;
    double s = Q[i * WC + j] + Q[i * WC + j + 1] +
               Q[(i + 1) * WC + j] + Q[(i + 1) * WC + j + 1];
    double inv1 = 1.0 / sqrt(s + EPS2);
    double inv2 = 1.0 / sqrt(s2[i * NBC + j] + EPS2);
    double v = (double)cell[(((size_t)n * NBINS + b) * HC + i + di) * WC + j + dj] * inv1;
    v = fmin(v, 0.2);
    out[idx] = (float)(v * inv2);
}

// ---------------------------------------------------------------------------
extern "C" void kernel_launch(void* const* d_in, const int* in_sizes, int n_in,
                              void* d_out, int out_size, void* d_ws, size_t ws_size,
                              hipStream_t stream) {
    const float* img = (const float*)d_in[0];   // (32,1,512,512) f32
    float* out = (float*)d_out;

    float*  cell = (float*)d_ws;                          // 32*10*64*64 f32
    double* Q    = (double*)(cell + (size_t)NB * NBINS * HC * WC);  // 64*64 f64
    double* s2   = Q + HC * WC;                           // 63*63 f64

    hipLaunchKernelGGL(k_init, dim3(16), dim3(256), 0, stream, Q, s2);
    hipLaunchKernelGGL(k_cellhist, dim3(HC, 2, NB), dim3(64), 0, stream, img, cell);
    hipLaunchKernelGGL(k_Q, dim3(HC, 10), dim3(64), 0, stream, cell, Q);
    hipLaunchKernelGGL(k_s2, dim3(NBR, 20), dim3(64), 0, stream, cell, Q, s2);
    const int total = NB * NBINS * 2 * 2 * NBR * NBC;
    hipLaunchKernelGGL(k_out, dim3((total + 255) / 256), dim3(256), 0, stream,
                       cell, Q, s2, out);
}

// Round 5
// 147.775 us; speedup vs baseline: 1.5906x; 1.1380x over previous
//
#include <hip/hip_runtime.h>
#include <math.h>

#define NBINS 10
#define NB    32
#define HH    512
#define WW    512
#define HC    64
#define WC    64
#define NBR   63
#define NBC   63
#define EPS2  1e-10       // EPS^2, EPS=1e-5

// ---------------------------------------------------------------------------
// K1: fused Sobel + binning + 8x8 mean pool -> cell[n][bin][cy][cx] (f32)
// Block = (cy, n): 256 threads / 4 waves, full 512-wide strip in LDS.
// 4 threads per cell (sub = t&3 -> pixel rows {1,2},{3,4},{5,6},{7,8}),
// merged via shfl_xor(1), shfl_xor(2).
// LDS stride 516 (== 4 mod 32) + stagger px = (k + 2*w2 + sub) & 7 gives
// provably <=2 lanes/bank on every ds_read_b32 (free on CDNA4).
// Bin decisions bit-identical to the PASSING round-3/4 kernels:
//   fast: f32 conv chain + atan2f + /pi32 *10, guard band 1e-4
//   fallback: (float)atan2(double,double) exact emulation (same conv values)
// ---------------------------------------------------------------------------
__global__ __launch_bounds__(256) void k_cellhist(const float* __restrict__ img,
                                                  float* __restrict__ cell) {
    const int cy = blockIdx.x;   // 0..63
    const int n  = blockIdx.y;   // 0..31
    const int t  = threadIdx.x;  // 0..255

    __shared__ float lds[10][516];

    const float* im = img + (size_t)n * HH * WW;
    const int gy0 = cy * 8 - 1;
    for (int idx = t; idx < 10 * 514; idx += 256) {
        int r  = idx / 514;
        int c  = idx - r * 514;          // lds col 0..513, img col = c-1
        int gr = gy0 + r, gc = c - 1;
        float v = 0.0f;
        if ((unsigned)gr < HH && (unsigned)gc < WW) v = im[gr * WW + gc];
        lds[r][c] = v;
    }
    __syncthreads();

    float hist[NBINS];
#pragma unroll
    for (int b = 0; b < NBINS; ++b) hist[b] = 0.0f;

    const float pi32 = (float)M_PI;          // 0x40490FDB
    const int cc   = t >> 2;                 // cell 0..63
    const int sub  = t & 3;
    const int r0   = 1 + 2 * sub;            // strip pixel rows r0, r0+1
    const int stag = 2 * ((t >> 4) & 3) + sub;

    for (int ry = 0; ry < 2; ++ry) {
        const int row = r0 + ry;
        for (int k = 0; k < 8; ++k) {
            const int px  = (k + stag) & 7;
            const int col = cc * 8 + px + 1;
            float a  = lds[row - 1][col - 1];
            float b  = lds[row - 1][col    ];
            float c  = lds[row - 1][col + 1];
            float d  = lds[row    ][col - 1];
            float f  = lds[row    ][col + 1];
            float g  = lds[row + 1][col - 1];
            float h  = lds[row + 1][col    ];
            float i2 = lds[row + 1][col + 1];
            // identical accumulation order to the passing round-3 kernel
            float gA = a;
            gA = gA - c;
            gA = gA + 2.0f * d;
            gA = gA - 2.0f * f;
            gA = gA + g;
            gA = gA - i2;
            float gB = a;
            gB = gB + 2.0f * b;
            gB = gB + c;
            gB = gB - g;
            gB = gB - 2.0f * h;
            gB = gB - i2;

            float mag = sqrtf(gA * gA + gB * gB);

            // fast bin decision with guard band
            float pbf = atan2f(gA, gB);
            pbf = pbf / pi32;
            pbf = pbf * 10.0f;
            float fr  = floorf(pbf);
            float dfr = pbf - fr;
            int fl, ce;
            if (dfr > 1e-4f && dfr < 0.9999f) {
                fl = (int)fr;
                ce = fl + 1;
            } else {
                // exact f32-emulation fallback (round-3 verified)
                float phase = (float)atan2((double)gA, (double)gB);
                float pb = phase / pi32;
                pb = pb * 10.0f;
                fl = (int)floorf(pb);
                ce = (int)ceilf(pb);
            }
            int flm = fl % NBINS; if (flm < 0) flm += NBINS;   // Python %
            int cem = ce % NBINS; if (cem < 0) cem += NBINS;
            hist[flm] += mag;
            hist[cem] += 1.0f - mag;
        }
    }

    // merge the 4 per-thread partials of each cell (lanes 4c..4c+3)
#pragma unroll
    for (int b = 0; b < NBINS; ++b) {
        hist[b] += __shfl_xor(hist[b], 1);
        hist[b] += __shfl_xor(hist[b], 2);
    }

    // each of the 4 threads writes bins b with (b & 3) == sub (coalesced in cc)
#pragma unroll
    for (int bb = 0; bb < NBINS; ++bb) {
        if ((bb & 3) == sub)
            cell[(((size_t)n * NBINS + bb) * HC + cy) * WC + cc] = hist[bb] * 0.015625f;
    }
}

// ---------------------------------------------------------------------------
// K2: Q[i][j] = sum over (n,bin) of cell^2, f64 atomic over nb-chunks
// ---------------------------------------------------------------------------
__global__ __launch_bounds__(64) void k_Q(const float* __restrict__ cell,
                                          double* __restrict__ Q) {
    const int i     = blockIdx.x;   // 0..63
    const int chunk = blockIdx.y;   // 0..9
    const int j     = threadIdx.x;  // 0..63
    double acc = 0.0;
    for (int nb = chunk * 32; nb < chunk * 32 + 32; ++nb) {
        double v = (double)cell[((size_t)nb * HC + i) * WC + j];
        acc += v * v;
    }
    atomicAdd(&Q[i * WC + j], acc);
}

// ---------------------------------------------------------------------------
// K4: s2[i][j] = sum over (n,bin,di,dj) of min(cell*inv1, 0.2)^2
// ---------------------------------------------------------------------------
__global__ __launch_bounds__(64) void k_s2(const float* __restrict__ cell,
                                           const double* __restrict__ Q,
                                           double* __restrict__ s2) {
    const int i     = blockIdx.x;   // 0..62
    const int chunk = blockIdx.y;   // 0..19
    const int j     = threadIdx.x;  // 0..63
    if (j >= NBC) return;
    double s = Q[i * WC + j] + Q[i * WC + j + 1] +
               Q[(i + 1) * WC + j] + Q[(i + 1) * WC + j + 1];
    double w = 1.0 / sqrt(s + EPS2);
    double acc = 0.0;
    for (int nb = chunk * 16; nb < chunk * 16 + 16; ++nb) {
#pragma unroll
        for (int di = 0; di < 2; ++di)
#pragma unroll
            for (int dj = 0; dj < 2; ++dj) {
                double v = (double)cell[((size_t)nb * HC + i + di) * WC + j + dj] * w;
                v = fmin(v, 0.2);
                acc += v * v;
            }
    }
    atomicAdd(&s2[i * NBC + j], acc);
}

// ---------------------------------------------------------------------------
// K6: final write out[n][bin][di][dj][i][j]; inv1/inv2 recomputed inline
// ---------------------------------------------------------------------------
__global__ void k_out(const float* __restrict__ cell,
                      const double* __restrict__ Q,
                      const double* __restrict__ s2,
                      float* __restrict__ out) {
    int idx = blockIdx.x * blockDim.x + threadIdx.x;
    const int total = NB * NBINS * 2 * 2 * NBR * NBC;
    if (idx >= total) return;
    int j   = idx % NBC;
    int tmp = idx / NBC;
    int i   = tmp % NBR; tmp /= NBR;
    int dj  = tmp % 2;   tmp /= 2;
    int di  = tmp % 2;   tmp /= 2;
    int b   = tmp % NBINS;
    int n   = tmp / NBINS;
    double s = Q[i * WC + j] + Q[i * WC + j + 1] +
               Q[(i + 1) * WC + j] + Q[(i + 1) * WC + j + 1];
    double inv1 = 1.0 / sqrt(s + EPS2);
    double inv2 = 1.0 / sqrt(s2[i * NBC + j] + EPS2);
    double v = (double)cell[(((size_t)n * NBINS + b) * HC + i + di) * WC + j + dj] * inv1;
    v = fmin(v, 0.2);
    out[idx] = (float)(v * inv2);
}

// ---------------------------------------------------------------------------
extern "C" void kernel_launch(void* const* d_in, const int* in_sizes, int n_in,
                              void* d_out, int out_size, void* d_ws, size_t ws_size,
                              hipStream_t stream) {
    const float* img = (const float*)d_in[0];   // (32,1,512,512) f32
    float* out = (float*)d_out;

    float*  cell = (float*)d_ws;                          // 32*10*64*64 f32
    double* Q    = (double*)(cell + (size_t)NB * NBINS * HC * WC);  // 64*64 f64
    double* s2   = Q + HC * WC;                           // 63*63 f64

    // zero the two f64 accumulators (contiguous) in one async memset
    hipMemsetAsync(Q, 0, (size_t)(HC * WC + NBR * NBC) * sizeof(double), stream);
    hipLaunchKernelGGL(k_cellhist, dim3(HC, NB), dim3(256), 0, stream, img, cell);
    hipLaunchKernelGGL(k_Q, dim3(HC, 10), dim3(64), 0, stream, cell, Q);
    hipLaunchKernelGGL(k_s2, dim3(NBR, 20), dim3(64), 0, stream, cell, Q, s2);
    const int total = NB * NBINS * 2 * 2 * NBR * NBC;
    hipLaunchKernelGGL(k_out, dim3((total + 255) / 256), dim3(256), 0, stream,
                       cell, Q, s2, out);
}

// Round 6
// 132.782 us; speedup vs baseline: 1.7702x; 1.1129x over previous
//
#include <hip/hip_runtime.h>
#include <math.h>

#define NBINS 10
#define NB    32
#define HH    512
#define WW    512
#define HC    64
#define WC    64
#define NBR   63
#define NBC   63
#define EPS2F 1e-10f      // EPS^2, EPS=1e-5

// ---------------------------------------------------------------------------
// K1: fused Sobel + binning + 8x8 mean pool + Q-partial
//   -> cell[n][bin][cy][cx] (f32), Q[cy][cx] += sum_b cell^2 (f32 atomics)
// Block = (cy, n): 256 threads / 4 waves, 4 threads per cell.
// Bin decision: EXACT cross-product sector finder (no atan2 on fast path).
//   fl = floor(atan2(gA,gB)/pi*10) is a 20-sector decision; by quadrant
//   symmetry idx = #{k in 1..4 : y*cos(k*pi/10) > x*sin(k*pi/10)} with
//   y=|gA|, x=|gB| gives the exact sector. Guard band 3.2e-5*mag rad
//   (== 1e-4 pb-units, the margin that passed rounds 3-5) falls back to
//   the bit-exact f32-emulation ((float)atan2(double,double)).
//   Outside the guard, exact sector == reference's f32 decision (ref pb
//   error ~3e-6 pb-units << 1e-4). Bin decisions provably unchanged.
// ---------------------------------------------------------------------------
__global__ __launch_bounds__(256) void k_cellhist(const float* __restrict__ img,
                                                  float* __restrict__ cell,
                                                  float* __restrict__ Q) {
    const int cy = blockIdx.x;   // 0..63
    const int n  = blockIdx.y;   // 0..31
    const int t  = threadIdx.x;  // 0..255

    __shared__ float lds[10][516];

    const float* im = img + (size_t)n * HH * WW;
    const int gy0 = cy * 8 - 1;
    for (int idx = t; idx < 10 * 514; idx += 256) {
        int r  = idx / 514;
        int c  = idx - r * 514;          // lds col 0..513, img col = c-1
        int gr = gy0 + r, gc = c - 1;
        float v = 0.0f;
        if ((unsigned)gr < HH && (unsigned)gc < WW) v = im[gr * WW + gc];
        lds[r][c] = v;
    }
    __syncthreads();

    float hist[NBINS];
#pragma unroll
    for (int b = 0; b < NBINS; ++b) hist[b] = 0.0f;

    const float pi32 = (float)M_PI;          // 0x40490FDB
    // sin/cos(k*pi/10), k=1..4
    const float S1 = 0.30901699f, C1 = 0.95105652f;
    const float S2 = 0.58778525f, C2 = 0.80901699f;
    const float S3 = 0.80901699f, C3 = 0.58778525f;
    const float S4 = 0.95105652f, C4 = 0.30901699f;

    const int cc   = t >> 2;                 // cell 0..63
    const int sub  = t & 3;
    const int r0   = 1 + 2 * sub;            // strip pixel rows r0, r0+1
    const int stag = 2 * ((t >> 4) & 3) + sub;

    for (int ry = 0; ry < 2; ++ry) {
        const int row = r0 + ry;
        for (int k = 0; k < 8; ++k) {
            const int px  = (k + stag) & 7;
            const int col = cc * 8 + px + 1;
            float a  = lds[row - 1][col - 1];
            float b  = lds[row - 1][col    ];
            float c  = lds[row - 1][col + 1];
            float d  = lds[row    ][col - 1];
            float f  = lds[row    ][col + 1];
            float g  = lds[row + 1][col - 1];
            float h  = lds[row + 1][col    ];
            float i2 = lds[row + 1][col + 1];
            // identical accumulation order to the passing round-3 kernel
            float gA = a;
            gA = gA - c;
            gA = gA + 2.0f * d;
            gA = gA - 2.0f * f;
            gA = gA + g;
            gA = gA - i2;
            float gB = a;
            gB = gB + 2.0f * b;
            gB = gB + c;
            gB = gB - g;
            gB = gB - 2.0f * h;
            gB = gB - i2;

            float mag = sqrtf(gA * gA + gB * gB);

            // exact sector via cross products (quadrant-reduced)
            float y = fabsf(gA), x = fabsf(gB);
            float cr1 = fmaf(y, C1, -(x * S1));
            float cr2 = fmaf(y, C2, -(x * S2));
            float cr3 = fmaf(y, C3, -(x * S3));
            float cr4 = fmaf(y, C4, -(x * S4));
            int idx = (cr1 > 0.0f) + (cr2 > 0.0f) + (cr3 > 0.0f) + (cr4 > 0.0f);
            float minc = fminf(fminf(y, x),
                               fminf(fminf(fabsf(cr1), fabsf(cr2)),
                                     fminf(fabsf(cr3), fabsf(cr4))));
            int flm, cem;
            if (minc > 3.2e-5f * mag) {
                // fast: exact sector, mapped per quadrant (Python-mod verified)
                bool same = (gA >= 0.0f) == (gB >= 0.0f);
                flm = same ? idx : 9 - idx;
                cem = same ? idx + 1 : (idx ? 10 - idx : 0);
            } else {
                // exact f32-emulation fallback (round-3 verified, bit-identical)
                float phase = (float)atan2((double)gA, (double)gB);
                float pb = phase / pi32;
                pb = pb * 10.0f;
                int fl = (int)floorf(pb);
                int ce = (int)ceilf(pb);
                flm = fl % NBINS; if (flm < 0) flm += NBINS;   // Python %
                cem = ce % NBINS; if (cem < 0) cem += NBINS;
            }
            hist[flm] += mag;
            hist[cem] += 1.0f - mag;
        }
    }

    // merge the 4 per-thread partials of each cell (lanes 4c..4c+3)
#pragma unroll
    for (int b = 0; b < NBINS; ++b) {
        hist[b] += __shfl_xor(hist[b], 1);
        hist[b] += __shfl_xor(hist[b], 2);
    }

    // write cell (each sub writes bins with (b&3)==sub, coalesced in cc)
#pragma unroll
    for (int bb = 0; bb < NBINS; ++bb) {
        if ((bb & 3) == sub)
            cell[(((size_t)n * NBINS + bb) * HC + cy) * WC + cc] = hist[bb] * 0.015625f;
    }
    // fused Q-partial: sub==0 lane of each cell adds sum_b cell^2
    if (sub == 0) {
        float q = 0.0f;
#pragma unroll
        for (int bb = 0; bb < NBINS; ++bb) {
            float cv = hist[bb] * 0.015625f;
            q = fmaf(cv, cv, q);
        }
        atomicAdd(&Q[cy * WC + cc], q);
    }
}

// ---------------------------------------------------------------------------
// K2: s2[i][j] = sum over (n,bin,di,dj) of min(cell*inv1, 0.2)^2   (f32)
// Block = (i, chunk): 256 threads = 64 j-lanes x 4 subs; 10 nb-groups each.
// ---------------------------------------------------------------------------
__global__ __launch_bounds__(256) void k_s2(const float* __restrict__ cell,
                                            const float* __restrict__ Q,
                                            float* __restrict__ s2) {
    const int i     = blockIdx.x;   // 0..62
    const int chunk = blockIdx.y;   // 0..7
    const int t     = threadIdx.x;
    const int j     = t & 63;
    const int sub   = t >> 6;       // 0..3
    if (j >= NBC) return;
    float s = Q[i * WC + j] + Q[i * WC + j + 1] +
              Q[(i + 1) * WC + j] + Q[(i + 1) * WC + j + 1];
    float w = 1.0f / sqrtf(s + EPS2F);
    float acc = 0.0f;
    const int nb0 = (chunk * 4 + sub) * 10;     // 32 slices x 10 nb
    for (int nb = nb0; nb < nb0 + 10; ++nb) {
        const float* base = cell + ((size_t)nb * HC + i) * WC + j;
        float v00 = base[0], v01 = base[1];
        float v10 = base[WC], v11 = base[WC + 1];
        v00 = fminf(v00 * w, 0.2f); acc = fmaf(v00, v00, acc);
        v01 = fminf(v01 * w, 0.2f); acc = fmaf(v01, v01, acc);
        v10 = fminf(v10 * w, 0.2f); acc = fmaf(v10, v10, acc);
        v11 = fminf(v11 * w, 0.2f); acc = fmaf(v11, v11, acc);
    }
    atomicAdd(&s2[i * NBC + j], acc);
}

// ---------------------------------------------------------------------------
// K3: inv1[ij] = 1/sqrt(s+eps^2), inv2[ij] = 1/sqrt(s2+eps^2)   (3969 elems)
// ---------------------------------------------------------------------------
__global__ void k_inv(const float* __restrict__ Q, const float* __restrict__ s2,
                      float* __restrict__ inv1, float* __restrict__ inv2) {
    int idx = blockIdx.x * blockDim.x + threadIdx.x;
    if (idx >= NBR * NBC) return;
    int i = idx / NBC, j = idx - i * NBC;
    float s = Q[i * WC + j] + Q[i * WC + j + 1] +
              Q[(i + 1) * WC + j] + Q[(i + 1) * WC + j + 1];
    inv1[idx] = 1.0f / sqrtf(s + EPS2F);
    inv2[idx] = 1.0f / sqrtf(s2[idx] + EPS2F);
}

// ---------------------------------------------------------------------------
// K4: final write out[n][bin][di][dj][i][j] — pure streaming f32
// ---------------------------------------------------------------------------
__global__ void k_out(const float* __restrict__ cell,
                      const float* __restrict__ inv1,
                      const float* __restrict__ inv2,
                      float* __restrict__ out) {
    int idx = blockIdx.x * blockDim.x + threadIdx.x;
    const int total = NB * NBINS * 2 * 2 * NBR * NBC;
    if (idx >= total) return;
    int ij  = idx % (NBR * NBC);
    int tmp = idx / (NBR * NBC);
    int j   = ij % NBC;
    int i   = ij / NBC;
    int dj  = tmp % 2;   tmp /= 2;
    int di  = tmp % 2;   tmp /= 2;
    int b   = tmp % NBINS;
    int n   = tmp / NBINS;
    float v = cell[(((size_t)n * NBINS + b) * HC + i + di) * WC + j + dj] * inv1[ij];
    v = fminf(v, 0.2f);
    out[idx] = v * inv2[ij];
}

// ---------------------------------------------------------------------------
extern "C" void kernel_launch(void* const* d_in, const int* in_sizes, int n_in,
                              void* d_out, int out_size, void* d_ws, size_t ws_size,
                              hipStream_t stream) {
    const float* img = (const float*)d_in[0];   // (32,1,512,512) f32
    float* out = (float*)d_out;

    float* cell = (float*)d_ws;                           // 32*10*64*64
    float* Q    = cell + (size_t)NB * NBINS * HC * WC;    // 64*64
    float* s2   = Q + HC * WC;                            // 63*63
    float* inv1 = s2 + NBR * NBC;                         // 63*63
    float* inv2 = inv1 + NBR * NBC;                       // 63*63

    // zero the two atomic accumulators (contiguous) in one async memset
    hipMemsetAsync(Q, 0, (size_t)(HC * WC + NBR * NBC) * sizeof(float), stream);
    hipLaunchKernelGGL(k_cellhist, dim3(HC, NB), dim3(256), 0, stream, img, cell, Q);
    hipLaunchKernelGGL(k_s2, dim3(NBR, 8), dim3(256), 0, stream, cell, Q, s2);
    hipLaunchKernelGGL(k_inv, dim3(16), dim3(256), 0, stream, Q, s2, inv1, inv2);
    const int total = NB * NBINS * 2 * 2 * NBR * NBC;
    hipLaunchKernelGGL(k_out, dim3((total + 255) / 256), dim3(256), 0, stream,
                       cell, inv1, inv2, out);
}